// Round 9
// baseline (62.243 us; speedup 1.0000x reference)
//
#include <hip/hip_runtime.h>

// Barnes-Wall Lambda16 quantizer — pair-split version: 2 threads per row.
//
// R8 post-mortem: latency-bound (VALUBusy 47%, occupancy 33% = 4 waves/SIMD,
// grid-limited). This round: each row is processed by a LANE PAIR.
//  - pass-1: each thread ranks 16 of the 32 candidates (surrogate Dtil,
//    R5..R8-validated math), keeps stable local top-3.
//  - merge: 6 shfl_xor + 3 stable inserts => exact global (dtil,k)-lex top-3
//    (all hi-half k > all lo-half k, so strict-< insert == lex merge).
//  - pass-2: t0 evals k1, t1 evals k2, both eval k3 (lanes lockstep anyway);
//    1 shuffle shares D's; winner by lexicographic (D,k) == numpy first-min.
//  - emit: both lanes run eval_k<true>(kb); each stores its 32B half-row.
// Occupancy: 524288 threads = 8192 waves = 8 waves/SIMD iff VGPR <= 64
// (m69 cliff) -> __launch_bounds__(256, 8). R8's identical per-thread
// machinery compiled to exactly 64 VGPRs.
//
// Pass-1 surrogate (validated absmax 0.0 in R5/R6/R7/R8):
//   dd0[j] = xh - rint(xh); dd1[j] = (xh-.5) - rint(xh-.5)  (mod-2 tables)
//   Dtil = sum d^2 + par * (1 - 2*max|d|)   ( = D_k/4 in reals )
//   par = (popcount((P1&O)|(P0&~O)) + par2(k)) & 1
//
// Pass-2 bit-exactness invariants (absmax must be 0.0):
//  - fp contract OFF; fmaf only where exact or single-rounding-identical:
//    fmaf(c,-0.5,xh) == fl(xh-c/2) == fl(fl(x-c)*0.5); fmaf(2,f,c) exact;
//    Xp = fmaf(bit,+-2,X) exact (integers).
//  - rintf == round-half-to-even == np.round; dd = x2 - f exact.
//  - first-max: contiguous-pair tournament, left wins ties (>=).
//  - corr = f + sign(dd) == ceil(xc)+floor(xc)-fc (incl. exact halves).
//  - e = Xp - x directly (single rounding); D in numpy's n=16 pairwise
//    order: r[j]=sq[j]+sq[j+8]; D=((r0+r1)+(r2+r3))+((r4+r5)+(r6+r7)).
//  - parity (pass-2): float sum-tree of integer-valued f (exact), cvt, &1.

constexpr int G5[5][16] = {
    {1,1,1,1,0,1,0,1,1,0,0,1,0,0,0,0},
    {0,1,1,1,1,0,1,0,1,1,0,0,1,0,0,0},
    {0,0,1,1,1,1,0,1,0,1,1,0,0,1,0,0},
    {0,0,0,1,1,1,1,0,1,0,1,1,0,0,1,0},
    {1,1,1,1,1,1,1,1,1,1,1,1,1,1,1,1}};

struct Masks { int m[16]; };
constexpr Masks make_masks() {
  Masks mk{};
  for (int j = 0; j < 16; ++j) {
    int m = 0;
    for (int i = 0; i < 5; ++i) m |= G5[i][j] << (4 - i);
    mk.m[j] = m;
  }
  return mk;
}
constexpr Masks mk = make_masks();

// Packed per-candidate word: bits 0..15 = odd-mask O(k), bit 16 = par2(k).
struct KW { unsigned w[32]; };
constexpr KW make_kw() {
  KW t{};
  for (int k = 0; k < 32; ++k) {
    unsigned om = 0, p2 = 0;
    for (int j = 0; j < 16; ++j) {
      int c = 0;
      for (int i = 0; i < 5; ++i) c += ((k >> (4 - i)) & 1) * G5[i][j];
      om |= (unsigned)(c & 1) << j;
      p2 ^= (unsigned)((c >> 1) & 1);
    }
    t.w[k] = om | (p2 << 16);
  }
  return t;
}
constexpr KW kwt = make_kw();

__device__ __forceinline__ int parity16i(const float (&f)[16]) {
  // exact: all addends are small integers
  float s0 = ((f[0] + f[1]) + (f[2] + f[3])) + ((f[4] + f[5]) + (f[6] + f[7]));
  float s1 = ((f[8] + f[9]) + (f[10] + f[11])) + ((f[12] + f[13]) + (f[14] + f[15]));
  return ((int)(s0 + s1)) & 1;
}

// Exact numpy-pipeline evaluation of candidate kk (R2..R8-verified).
template <bool EMIT>
__device__ __forceinline__ float eval_k(int kk, const float (&x)[16],
                                        const float (&xh)[16], float a,
                                        float (&y)[16]) {
#pragma clang fp contract(off)
  float f[16], dd[16];
#pragma unroll
  for (int j = 0; j < 16; ++j) {
    float c = (float)__builtin_popcount(kk & mk.m[j]);
    float x2 = __builtin_fmaf(c, -0.5f, xh[j]);  // == fl(xh - c/2)
    float fj = __builtin_rintf(x2);
    f[j] = fj;
    dd[j] = x2 - fj;                             // exact
  }
  const int par = parity16i(f);

  // first-occurrence argmax of |dd| -> onehot (left wins ties)
  float tv[16];
  int ti[16];
#pragma unroll
  for (int j = 0; j < 16; ++j) { tv[j] = __builtin_fabsf(dd[j]); ti[j] = 1 << j; }
#pragma unroll
  for (int w = 8; w >= 1; w >>= 1) {
#pragma unroll
    for (int j = 0; j < w; ++j) {
      bool L = tv[2 * j] >= tv[2 * j + 1];
      tv[j] = L ? tv[2 * j] : tv[2 * j + 1];
      ti[j] = L ? ti[2 * j] : ti[2 * j + 1];
    }
  }
  const int ohm = par ? ti[0] : 0;   // patch mask (0 when parity even)

  float sq[16];
#pragma unroll
  for (int j = 0; j < 16; ++j) {
    float c  = (float)__builtin_popcount(kk & mk.m[j]);
    float X  = __builtin_fmaf(2.0f, f[j], c);          // exact int
    float s2 = __builtin_copysignf(2.0f, dd[j]);       // corr direction
    float bitf = (float)((ohm >> j) & 1);
    float Xp = __builtin_fmaf(bitf, s2, X);            // exact int
    float e  = Xp - x[j];                              // single rounding
    sq[j] = e * e;
    if (EMIT) y[j] = Xp * a;
  }
  float r0 = sq[0] + sq[8],  r1 = sq[1] + sq[9];
  float r2 = sq[2] + sq[10], r3 = sq[3] + sq[11];
  float r4 = sq[4] + sq[12], r5 = sq[5] + sq[13];
  float r6 = sq[6] + sq[14], r7 = sq[7] + sq[15];
  return ((r0 + r1) + (r2 + r3)) + ((r4 + r5) + (r6 + r7));
}

__global__ __launch_bounds__(256, 8) void bw_quant_kernel(
    const float* __restrict__ x_in,
    const float* __restrict__ C_rep,   // unused (constexpr codebook)
    const float* __restrict__ a_ptr,
    float* __restrict__ y_out,
    int n_rows)
{
#pragma clang fp contract(off)
  __shared__ unsigned kw_lds[32];
  if (threadIdx.x < 32) kw_lds[threadIdx.x] = kwt.w[threadIdx.x];
  __syncthreads();

  const int gid = blockIdx.x * 256 + threadIdx.x;
  const int row = gid >> 1;
  const int half = gid & 1;        // which 16-candidate slice + which half-row store
  if (row >= n_rows) return;

  const float a = a_ptr[0];

  float x[16];
  {
    const float4* xr4 = reinterpret_cast<const float4*>(x_in + (size_t)row * 16);
#pragma unroll
    for (int q = 0; q < 4; ++q) {
      float4 v = xr4[q];
      x[q * 4 + 0] = v.x / a;
      x[q * 4 + 1] = v.y / a;
      x[q * 4 + 2] = v.z / a;
      x[q * 4 + 3] = v.w / a;
    }
  }

  // -------- mod-2 signed residual tables + parity masks (pass-1) ----------
  float dd0[16], dd1[16];
  int P0 = 0, P1 = 0;   // bit j = parity of rint(xh_j) / rint(xh_j - 0.5)
#pragma unroll
  for (int j = 0; j < 16; ++j) {
    float xh = x[j] * 0.5f;                 // exact
    float t0 = __builtin_rintf(xh);
    dd0[j] = xh - t0;
    float h  = xh - 0.5f;
    float t1 = __builtin_rintf(h);
    dd1[j] = h - t1;
    P0 |= ((int)t0 & 1) << j;
    P1 |= ((int)t1 & 1) << j;
  }

  // -------- pass 1: surrogate ranking over MY 16 candidates ---------------
  float b1 = __builtin_inff(), b2 = b1, b3 = b1;
  int k1 = 0, k2 = 0, k3 = 0;
  const int kbase = half << 4;

#pragma unroll 1
  for (int i = 0; i < 16; ++i) {
    const int k = kbase + i;
    const unsigned w = kw_lds[k];       // 2 distinct addrs/wave -> broadcast
    const unsigned O = w & 0xFFFFu;
    const int p2 = (int)(w >> 16);

    float d[16];
#pragma unroll
    for (int j = 0; j < 16; ++j)
      d[j] = ((O >> j) & 1u) ? dd1[j] : dd0[j];

    // ssum = sum d^2 : 4 parallel fma chains (surrogate precision)
    float s0 = __builtin_fmaf(d[0], d[0], __builtin_fmaf(d[1], d[1],
               __builtin_fmaf(d[2], d[2], d[3] * d[3])));
    float s1 = __builtin_fmaf(d[4], d[4], __builtin_fmaf(d[5], d[5],
               __builtin_fmaf(d[6], d[6], d[7] * d[7])));
    float s2 = __builtin_fmaf(d[8], d[8], __builtin_fmaf(d[9], d[9],
               __builtin_fmaf(d[10], d[10], d[11] * d[11])));
    float s3 = __builtin_fmaf(d[12], d[12], __builtin_fmaf(d[13], d[13],
               __builtin_fmaf(d[14], d[14], d[15] * d[15])));
    float s = (s0 + s1) + (s2 + s3);

    // mx = max |d| via v_max3 triples (abs folds as VOP3 src modifiers)
    float t0 = __builtin_fmaxf(__builtin_fmaxf(__builtin_fabsf(d[0]),  __builtin_fabsf(d[1])),  __builtin_fabsf(d[2]));
    float t1 = __builtin_fmaxf(__builtin_fmaxf(__builtin_fabsf(d[3]),  __builtin_fabsf(d[4])),  __builtin_fabsf(d[5]));
    float t2 = __builtin_fmaxf(__builtin_fmaxf(__builtin_fabsf(d[6]),  __builtin_fabsf(d[7])),  __builtin_fabsf(d[8]));
    float t3 = __builtin_fmaxf(__builtin_fmaxf(__builtin_fabsf(d[9]),  __builtin_fabsf(d[10])), __builtin_fabsf(d[11]));
    float t4 = __builtin_fmaxf(__builtin_fmaxf(__builtin_fabsf(d[12]), __builtin_fabsf(d[13])), __builtin_fabsf(d[14]));
    float mx = __builtin_fmaxf(__builtin_fmaxf(__builtin_fmaxf(t0, t1), t2),
                               __builtin_fmaxf(__builtin_fmaxf(t3, t4), __builtin_fabsf(d[15])));

    // mask parity (R5..R8-validated)
    unsigned sel = (O & (unsigned)P1) | (~O & (unsigned)P0);
    int cnt = __builtin_popcount(sel) + p2;
    float spen = s + __builtin_fmaf(-2.0f, mx, 1.0f);
    float dtil = (cnt & 1) ? spen : s;

    // stable top-3 insert (strict <: earlier k wins ties)
    bool lt1 = dtil < b1, lt2 = dtil < b2, lt3 = dtil < b3;
    float nb3 = lt3 ? (lt2 ? b2 : dtil) : b3;  int nk3 = lt3 ? (lt2 ? k2 : k) : k3;
    float nb2 = lt2 ? (lt1 ? b1 : dtil) : b2;  int nk2 = lt2 ? (lt1 ? k1 : k) : k2;
    b3 = nb3; k3 = nk3;
    b2 = nb2; k2 = nk2;
    b1 = lt1 ? dtil : b1;  k1 = lt1 ? k : k1;
  }

  // -------- merge the pair's top-3 lists (exact (dtil,k)-lex top-3) -------
  {
    float pb1 = __shfl_xor(b1, 1), pb2 = __shfl_xor(b2, 1), pb3 = __shfl_xor(b3, 1);
    int   pk1 = __shfl_xor(k1, 1), pk2 = __shfl_xor(k2, 1), pk3 = __shfl_xor(k3, 1);
    // lo list (k in [0,16)) as base; hi elements inserted with strict <
    // (all hi.k > all lo.k => strict < is exact lex merge, stable).
    float lb1 = half ? pb1 : b1, lb2 = half ? pb2 : b2, lb3 = half ? pb3 : b3;
    int   lk1 = half ? pk1 : k1, lk2 = half ? pk2 : k2, lk3 = half ? pk3 : k3;
    float hb1 = half ? b1 : pb1, hb2 = half ? b2 : pb2, hb3 = half ? b3 : pb3;
    int   hk1 = half ? k1 : pk1, hk2 = half ? k2 : pk2, hk3 = half ? k3 : pk3;

    b1 = lb1; b2 = lb2; b3 = lb3; k1 = lk1; k2 = lk2; k3 = lk3;
#pragma unroll
    for (int t = 0; t < 3; ++t) {
      float hv = (t == 0) ? hb1 : (t == 1) ? hb2 : hb3;
      int   hk = (t == 0) ? hk1 : (t == 1) ? hk2 : hk3;
      bool lt1_ = hv < b1, lt2_ = hv < b2, lt3_ = hv < b3;
      float nb3 = lt3_ ? (lt2_ ? b2 : hv) : b3;  int nk3 = lt3_ ? (lt2_ ? k2 : hk) : k3;
      float nb2 = lt2_ ? (lt1_ ? b1 : hv) : b2;  int nk2 = lt2_ ? (lt1_ ? k1 : hk) : k2;
      b3 = nb3; k3 = nk3;
      b2 = nb2; k2 = nk2;
      b1 = lt1_ ? hv : b1;  k1 = lt1_ ? hk : k1;
    }
  }

  // -------- pass 2: split exact evaluation (t0: k1, t1: k2, both: k3) -----
  float xh[16];
#pragma unroll
  for (int j = 0; j < 16; ++j) xh[j] = x[j] * 0.5f;   // exact

  float ydummy[16];
  const int kA = half ? k2 : k1;
  float DA = eval_k<false>(kA, x, xh, a, ydummy);
  float DB = eval_k<false>(k3, x, xh, a, ydummy);
  float DAp = __shfl_xor(DA, 1);
  float D1 = half ? DAp : DA;
  float D2 = half ? DA : DAp;
  float D3 = DB;

  // lexicographic (D, k) == numpy first-min over the candidate set
  bool c2 = (D2 < D1) || (D2 == D1 && k2 < k1);
  float Db = c2 ? D2 : D1;
  int kb = c2 ? k2 : k1;
  bool c3 = (D3 < Db) || (D3 == Db && k3 < kb);
  kb = c3 ? k3 : kb;

  // -------- emit: exact re-eval of the winner; store my half-row ----------
  float y[16];
  (void)eval_k<true>(kb, x, xh, a, y);

  float4 v0, v1;
  v0.x = half ? y[8]  : y[0];  v0.y = half ? y[9]  : y[1];
  v0.z = half ? y[10] : y[2];  v0.w = half ? y[11] : y[3];
  v1.x = half ? y[12] : y[4];  v1.y = half ? y[13] : y[5];
  v1.z = half ? y[14] : y[6];  v1.w = half ? y[15] : y[7];
  float4* dst = reinterpret_cast<float4*>(y_out + (size_t)row * 16 + half * 8);
  dst[0] = v0;
  dst[1] = v1;
}

extern "C" void kernel_launch(void* const* d_in, const int* in_sizes, int n_in,
                              void* d_out, int out_size, void* d_ws, size_t ws_size,
                              hipStream_t stream) {
  const float* x_in  = (const float*)d_in[0];
  const float* C_rep = (const float*)d_in[1];
  const float* a_ptr = (const float*)d_in[2];
  float* y_out = (float*)d_out;

  const int n_rows = in_sizes[0] / 16;
  const int block = 256;
  const int grid = (n_rows * 2 + block - 1) / block;
  bw_quant_kernel<<<grid, block, 0, stream>>>(x_in, C_rep, a_ptr, y_out, n_rows);
}

// Round 10
// 33.136 us; speedup vs baseline: 1.8784x; 1.8784x over previous
//
#include <hip/hip_runtime.h>

// Barnes-Wall Lambda16 quantizer — chunked-unroll pass-1 (latency fix) +
// bit-exact pass-2. Structure = R8 (best-validated math) with pass-1
// processed in chunks of 4 candidates per s_load_dwordx4.
//
// R7/R8 post-mortem: 47% VALUBusy at 4 waves/SIMD (grid-capped) — the
// rolled loop's per-iteration s_load + lgkmcnt(0) stall (~100-200cy L2)
// can't be hidden by TLP. Fix: 1 dwordx4 scalar load per 4 candidates,
// inner 4 bodies unrolled (static indexing), outer 8-loop unroll 2 ->
// loads overlap the previous chunk's ~250-instr compute. VGPR headroom:
// grid caps occupancy at 4 waves/SIMD regardless, so anything <=128 VGPRs
// (launch_bounds(256,4)) is free. R9 lesson: never constrain below the
// ~64-100 VGPR working set (spill collapse).
//
// Pass-1 surrogate (validated absmax 0.0 in R5..R9):
//   dd0[j] = xh - rint(xh); dd1[j] = (xh-.5) - rint(xh-.5)  (mod-2 tables)
//   d[j] = O(k)_j ? dd1[j] : dd0[j]
//   Dtil = sum d^2 + par * (1 - 2*max|d|)   ( = D_k/4 in reals )
//   par = (popcount((P1&O)|(P0&~O)) + par2(k)) & 1
// Keep stable top-3 (strict <, earlier k wins ties).
//
// Pass 2: bit-exact numpy pipeline eval_k (R2..R9-verified) on the 3
// survivors; winner by lexicographic (D,k) == numpy first-min; emit eval.
//
// Pass-2 bit-exactness invariants (absmax must be 0.0):
//  - fp contract OFF; fmaf only where exact or single-rounding-identical:
//    fmaf(c,-0.5,xh) == fl(xh-c/2) == fl(fl(x-c)*0.5); fmaf(2,f,c) exact;
//    Xp = fmaf(bit,+-2,X) exact (integers).
//  - rintf == round-half-to-even == np.round; dd = x2 - f exact.
//  - first-max: contiguous-pair tournament, left wins ties (>=).
//  - corr = f + sign(dd) == ceil(xc)+floor(xc)-fc (incl. exact halves).
//  - e = Xp - x directly (single rounding); D in numpy's n=16 pairwise
//    order: r[j]=sq[j]+sq[j+8]; D=((r0+r1)+(r2+r3))+((r4+r5)+(r6+r7)).
//  - parity (pass-2): float sum-tree of integer-valued f (exact), cvt, &1.

constexpr int G5[5][16] = {
    {1,1,1,1,0,1,0,1,1,0,0,1,0,0,0,0},
    {0,1,1,1,1,0,1,0,1,1,0,0,1,0,0,0},
    {0,0,1,1,1,1,0,1,0,1,1,0,0,1,0,0},
    {0,0,0,1,1,1,1,0,1,0,1,1,0,0,1,0},
    {1,1,1,1,1,1,1,1,1,1,1,1,1,1,1,1}};

struct Masks { int m[16]; };
constexpr Masks make_masks() {
  Masks mk{};
  for (int j = 0; j < 16; ++j) {
    int m = 0;
    for (int i = 0; i < 5; ++i) m |= G5[i][j] << (4 - i);
    mk.m[j] = m;
  }
  return mk;
}
constexpr Masks mk = make_masks();

// Packed per-candidate word: bits 0..15 = odd-mask O(k), bit 16 = par2(k).
struct alignas(16) KW { unsigned w[32]; };
constexpr KW make_kw() {
  KW t{};
  for (int k = 0; k < 32; ++k) {
    unsigned om = 0, p2 = 0;
    for (int j = 0; j < 16; ++j) {
      int c = 0;
      for (int i = 0; i < 5; ++i) c += ((k >> (4 - i)) & 1) * G5[i][j];
      om |= (unsigned)(c & 1) << j;
      p2 ^= (unsigned)((c >> 1) & 1);
    }
    t.w[k] = om | (p2 << 16);
  }
  return t;
}
constexpr KW kwt = make_kw();

__device__ __forceinline__ int parity16i(const float (&f)[16]) {
  // exact: all addends are small integers
  float s0 = ((f[0] + f[1]) + (f[2] + f[3])) + ((f[4] + f[5]) + (f[6] + f[7]));
  float s1 = ((f[8] + f[9]) + (f[10] + f[11])) + ((f[12] + f[13]) + (f[14] + f[15]));
  return ((int)(s0 + s1)) & 1;
}

// Exact numpy-pipeline evaluation of candidate kk (R2..R9-verified).
template <bool EMIT>
__device__ __forceinline__ float eval_k(int kk, const float (&x)[16],
                                        const float (&xh)[16], float a,
                                        float (&y)[16]) {
#pragma clang fp contract(off)
  float f[16], dd[16];
#pragma unroll
  for (int j = 0; j < 16; ++j) {
    float c = (float)__builtin_popcount(kk & mk.m[j]);
    float x2 = __builtin_fmaf(c, -0.5f, xh[j]);  // == fl(xh - c/2)
    float fj = __builtin_rintf(x2);
    f[j] = fj;
    dd[j] = x2 - fj;                             // exact
  }
  const int par = parity16i(f);

  // first-occurrence argmax of |dd| -> onehot (left wins ties)
  float tv[16];
  int ti[16];
#pragma unroll
  for (int j = 0; j < 16; ++j) { tv[j] = __builtin_fabsf(dd[j]); ti[j] = 1 << j; }
#pragma unroll
  for (int w = 8; w >= 1; w >>= 1) {
#pragma unroll
    for (int j = 0; j < w; ++j) {
      bool L = tv[2 * j] >= tv[2 * j + 1];
      tv[j] = L ? tv[2 * j] : tv[2 * j + 1];
      ti[j] = L ? ti[2 * j] : ti[2 * j + 1];
    }
  }
  const int ohm = par ? ti[0] : 0;   // patch mask (0 when parity even)

  float sq[16];
#pragma unroll
  for (int j = 0; j < 16; ++j) {
    float c  = (float)__builtin_popcount(kk & mk.m[j]);
    float X  = __builtin_fmaf(2.0f, f[j], c);          // exact int
    float s2 = __builtin_copysignf(2.0f, dd[j]);       // corr direction
    float bitf = (float)((ohm >> j) & 1);
    float Xp = __builtin_fmaf(bitf, s2, X);            // exact int
    float e  = Xp - x[j];                              // single rounding
    sq[j] = e * e;
    if (EMIT) y[j] = Xp * a;
  }
  float r0 = sq[0] + sq[8],  r1 = sq[1] + sq[9];
  float r2 = sq[2] + sq[10], r3 = sq[3] + sq[11];
  float r4 = sq[4] + sq[12], r5 = sq[5] + sq[13];
  float r6 = sq[6] + sq[14], r7 = sq[7] + sq[15];
  return ((r0 + r1) + (r2 + r3)) + ((r4 + r5) + (r6 + r7));
}

__global__ __launch_bounds__(256, 4) void bw_quant_kernel(
    const float* __restrict__ x_in,
    const float* __restrict__ C_rep,   // unused (constexpr codebook)
    const float* __restrict__ a_ptr,
    float* __restrict__ y_out,
    int n_rows)
{
#pragma clang fp contract(off)
  const int row = blockIdx.x * 256 + threadIdx.x;
  if (row >= n_rows) return;

  const float a = a_ptr[0];

  float x[16];
  {
    const float4* xr4 = reinterpret_cast<const float4*>(x_in + (size_t)row * 16);
#pragma unroll
    for (int q = 0; q < 4; ++q) {
      float4 v = xr4[q];
      x[q * 4 + 0] = v.x / a;
      x[q * 4 + 1] = v.y / a;
      x[q * 4 + 2] = v.z / a;
      x[q * 4 + 3] = v.w / a;
    }
  }

  // -------- mod-2 signed residual tables + parity masks (pass-1) ----------
  float dd0[16], dd1[16];
  int P0 = 0, P1 = 0;   // bit j = parity of rint(xh_j) / rint(xh_j - 0.5)
#pragma unroll
  for (int j = 0; j < 16; ++j) {
    float xh = x[j] * 0.5f;                 // exact
    float t0 = __builtin_rintf(xh);
    dd0[j] = xh - t0;
    float h  = xh - 0.5f;
    float t1 = __builtin_rintf(h);
    dd1[j] = h - t1;
    P0 |= ((int)t0 & 1) << j;
    P1 |= ((int)t1 & 1) << j;
  }

  // -------- pass 1: surrogate ranking, chunks of 4, keep stable top-3 -----
  float b1 = __builtin_inff(), b2 = b1, b3 = b1;
  int k1 = 0, k2 = 0, k3 = 0;

#pragma unroll 2
  for (int c = 0; c < 8; ++c) {
    // one scalar dwordx4 per 4 candidates (16B-aligned constexpr table)
    const uint4 w4 = *reinterpret_cast<const uint4*>(&kwt.w[c << 2]);
    const unsigned ws[4] = {w4.x, w4.y, w4.z, w4.w};

#pragma unroll
    for (int t = 0; t < 4; ++t) {
      const int k = (c << 2) + t;
      const unsigned w = ws[t];         // static index after unroll
      const unsigned O = w & 0xFFFFu;
      const int p2 = (int)(w >> 16);

      float d[16];
#pragma unroll
      for (int j = 0; j < 16; ++j)
        d[j] = ((O >> j) & 1u) ? dd1[j] : dd0[j];

      // ssum = sum d^2 : 4 parallel fma chains (surrogate precision)
      float s0 = __builtin_fmaf(d[0], d[0], __builtin_fmaf(d[1], d[1],
                 __builtin_fmaf(d[2], d[2], d[3] * d[3])));
      float s1 = __builtin_fmaf(d[4], d[4], __builtin_fmaf(d[5], d[5],
                 __builtin_fmaf(d[6], d[6], d[7] * d[7])));
      float s2 = __builtin_fmaf(d[8], d[8], __builtin_fmaf(d[9], d[9],
                 __builtin_fmaf(d[10], d[10], d[11] * d[11])));
      float s3 = __builtin_fmaf(d[12], d[12], __builtin_fmaf(d[13], d[13],
                 __builtin_fmaf(d[14], d[14], d[15] * d[15])));
      float s = (s0 + s1) + (s2 + s3);

      // mx = max |d| via v_max3 triples (abs folds as VOP3 src modifiers)
      float t0 = __builtin_fmaxf(__builtin_fmaxf(__builtin_fabsf(d[0]),  __builtin_fabsf(d[1])),  __builtin_fabsf(d[2]));
      float t1 = __builtin_fmaxf(__builtin_fmaxf(__builtin_fabsf(d[3]),  __builtin_fabsf(d[4])),  __builtin_fabsf(d[5]));
      float t2 = __builtin_fmaxf(__builtin_fmaxf(__builtin_fabsf(d[6]),  __builtin_fabsf(d[7])),  __builtin_fabsf(d[8]));
      float t3 = __builtin_fmaxf(__builtin_fmaxf(__builtin_fabsf(d[9]),  __builtin_fabsf(d[10])), __builtin_fabsf(d[11]));
      float t4 = __builtin_fmaxf(__builtin_fmaxf(__builtin_fabsf(d[12]), __builtin_fabsf(d[13])), __builtin_fabsf(d[14]));
      float mx = __builtin_fmaxf(__builtin_fmaxf(__builtin_fmaxf(t0, t1), t2),
                                 __builtin_fmaxf(__builtin_fmaxf(t3, t4), __builtin_fabsf(d[15])));

      // mask parity (R5..R9-validated)
      unsigned sel = (O & (unsigned)P1) | (~O & (unsigned)P0);
      int cnt = __builtin_popcount(sel) + p2;
      float spen = s + __builtin_fmaf(-2.0f, mx, 1.0f);
      float dtil = (cnt & 1) ? spen : s;

      // stable top-3 insert (strict <: earlier k wins ties)
      bool lt1 = dtil < b1, lt2 = dtil < b2, lt3 = dtil < b3;
      float nb3 = lt3 ? (lt2 ? b2 : dtil) : b3;  int nk3 = lt3 ? (lt2 ? k2 : k) : k3;
      float nb2 = lt2 ? (lt1 ? b1 : dtil) : b2;  int nk2 = lt2 ? (lt1 ? k1 : k) : k2;
      b3 = nb3; k3 = nk3;
      b2 = nb2; k2 = nk2;
      b1 = lt1 ? dtil : b1;  k1 = lt1 ? k : k1;
    }
  }

  // -------- pass 2: exact evaluation of the 3 survivors -------------------
  float xh[16];
#pragma unroll
  for (int j = 0; j < 16; ++j) xh[j] = x[j] * 0.5f;   // exact

  float ydummy[16];
  float D1 = eval_k<false>(k1, x, xh, a, ydummy);
  float D2 = eval_k<false>(k2, x, xh, a, ydummy);
  float D3 = eval_k<false>(k3, x, xh, a, ydummy);

  // lexicographic (D, k) == numpy first-min over the candidate set
  bool c2 = (D2 < D1) || (D2 == D1 && k2 < k1);
  float Db = c2 ? D2 : D1;
  int kb = c2 ? k2 : k1;
  bool c3 = (D3 < Db) || (D3 == Db && k3 < kb);
  kb = c3 ? k3 : kb;

  // -------- emit: exact re-eval of the winner -----------------------------
  float y[16];
  (void)eval_k<true>(kb, x, xh, a, y);

  float4* yr4 = reinterpret_cast<float4*>(y_out + (size_t)row * 16);
#pragma unroll
  for (int q = 0; q < 4; ++q) {
    float4 v;
    v.x = y[q * 4 + 0]; v.y = y[q * 4 + 1];
    v.z = y[q * 4 + 2]; v.w = y[q * 4 + 3];
    yr4[q] = v;
  }
}

extern "C" void kernel_launch(void* const* d_in, const int* in_sizes, int n_in,
                              void* d_out, int out_size, void* d_ws, size_t ws_size,
                              hipStream_t stream) {
  const float* x_in  = (const float*)d_in[0];
  const float* C_rep = (const float*)d_in[1];
  const float* a_ptr = (const float*)d_in[2];
  float* y_out = (float*)d_out;

  const int n_rows = in_sizes[0] / 16;
  const int block = 256;
  const int grid = (n_rows + block - 1) / block;
  bw_quant_kernel<<<grid, block, 0, stream>>>(x_in, C_rep, a_ptr, y_out, n_rows);
}

// Round 11
// 24.330 us; speedup vs baseline: 2.5582x; 1.3619x over previous
//
#include <hip/hip_runtime.h>

// Barnes-Wall Lambda16 quantizer — WHT-ssum pass-1 + LDS-codebook pass-2.
//
// Pass 1 (surrogate, fully unrolled, ZERO memory ops):
//   RM(1,4) structure: O(k)_j = k4 XOR <kappa, pt_j> where pt_j = column j of
//   generator rows 0..3 (all 16 points of F2^4), k4 = k&1 (all-ones row),
//   kappa = k>>1. Hence
//     ssum(k) = k4 ? S1 - h[kappa] : S0 + h[kappa],
//   h[kappa] = sum_{j: <kappa,pt_j>=1} delta_j, delta = dd1^2 - dd0^2,
//   computed for all 16 kappa at once via fast WHT (4 stages, 64 adds):
//     h[kappa] = 0.5*(W[0] - W[kappa]),  W = WHT(delta re-indexed by point).
//   Dtil = ssum + par*(1-2*max|d_sel|); d_sel via literal-O cndmask + max3
//   (R10 pattern); mask parity par = (popcount((P1&O)|(P0&~O))+par2)&1
//   (R5..R10-validated). Stable top-3 (strict <, earlier k wins ties).
//
// Pass 2 (bit-exact, R2..R10-verified semantics):
//   x/xh are NOT kept across pass-1 (register budget: persistent ~60 <= 64,
//   R10's proven envelope). Reload x_in + re-divide (identical fl ops ->
//   identical bits; L2-hot). eval_k reads the survivor's codeword row from
//   LDS (4x ds_read_b128) instead of per-j popcount, and uses
//   e = fmaf(-2, xh, Xp) == Xp - x (x = 2*xh exact) so x is never held.
//   3 evals + lexicographic (D,k) + emit re-eval of the winner.
//
// Pass-2 bit-exactness invariants (absmax must be 0.0):
//  - fp contract OFF; fmaf only where exact or single-rounding-identical:
//    fmaf(c,-0.5,xh) == fl(xh-c/2); fmaf(2,f,c) exact; Xp=fmaf(bit,+-2,X)
//    exact; e = fmaf(-2,xh,Xp) == fl(Xp - x) single rounding.
//  - rintf == round-half-to-even == np.round; dd = x2 - f exact.
//  - first-max: contiguous-pair tournament, left wins ties (>=).
//  - parity (pass-2): float sum-tree of integer-valued f (exact), cvt, &1.
//    (Mask parity is pass-1/surrogate ONLY — binade effects make it unsafe
//    for the exact pipeline.)
//  - D in numpy's n=16 pairwise order:
//    r[j]=sq[j]+sq[j+8]; D=((r0+r1)+(r2+r3))+((r4+r5)+(r6+r7)).

constexpr int G5[5][16] = {
    {1,1,1,1,0,1,0,1,1,0,0,1,0,0,0,0},
    {0,1,1,1,1,0,1,0,1,1,0,0,1,0,0,0},
    {0,0,1,1,1,1,0,1,0,1,1,0,0,1,0,0},
    {0,0,0,1,1,1,1,0,1,0,1,1,0,0,1,0},
    {1,1,1,1,1,1,1,1,1,1,1,1,1,1,1,1}};

struct Tabs {
  int m[16];       // column bit-masks: c_j(k) = popcount(k & m[j])
  unsigned w[32];  // bits 0..15 = odd-mask O(k), bit 16 = par2(k)
  int pt[16];      // pt[j] = 4-bit point (rows 0..3 at column j)
};
constexpr Tabs make_tabs() {
  Tabs t{};
  for (int j = 0; j < 16; ++j) {
    int m = 0;
    for (int i = 0; i < 5; ++i) m |= G5[i][j] << (4 - i);
    t.m[j] = m;
    t.pt[j] = (G5[0][j] << 3) | (G5[1][j] << 2) | (G5[2][j] << 1) | G5[3][j];
  }
  for (int k = 0; k < 32; ++k) {
    unsigned om = 0, p2 = 0;
    for (int j = 0; j < 16; ++j) {
      int c = 0;
      for (int i = 0; i < 5; ++i) c += ((k >> (4 - i)) & 1) * G5[i][j];
      om |= (unsigned)(c & 1) << j;
      p2 ^= (unsigned)((c >> 1) & 1);
    }
    t.w[k] = om | (p2 << 16);
  }
  return t;
}
constexpr Tabs tb = make_tabs();

__device__ __forceinline__ int parity16i(const float (&f)[16]) {
  // exact: all addends are small integers
  float s0 = ((f[0] + f[1]) + (f[2] + f[3])) + ((f[4] + f[5]) + (f[6] + f[7]));
  float s1 = ((f[8] + f[9]) + (f[10] + f[11])) + ((f[12] + f[13]) + (f[14] + f[15]));
  return ((int)(s0 + s1)) & 1;
}

// Exact numpy-pipeline evaluation of candidate kk. Codeword row from LDS.
template <bool EMIT>
__device__ __forceinline__ float eval_k(int kk, const float (&xh)[16], float a,
                                        float (&y)[16], const float (*Cs)[16]) {
#pragma clang fp contract(off)
  float cf[16];
  {
    const float4* crow = reinterpret_cast<const float4*>(&Cs[kk][0]);
    float4 c0 = crow[0], c1 = crow[1], c2 = crow[2], c3 = crow[3];
    cf[0] = c0.x; cf[1] = c0.y; cf[2] = c0.z; cf[3] = c0.w;
    cf[4] = c1.x; cf[5] = c1.y; cf[6] = c1.z; cf[7] = c1.w;
    cf[8] = c2.x; cf[9] = c2.y; cf[10] = c2.z; cf[11] = c2.w;
    cf[12] = c3.x; cf[13] = c3.y; cf[14] = c3.z; cf[15] = c3.w;
  }
  float f[16], dd[16];
#pragma unroll
  for (int j = 0; j < 16; ++j) {
    float x2 = __builtin_fmaf(cf[j], -0.5f, xh[j]);  // == fl(xh - c/2)
    float fj = __builtin_rintf(x2);
    f[j] = fj;
    dd[j] = x2 - fj;                                 // exact
  }
  const int par = parity16i(f);

  // first-occurrence argmax of |dd| -> onehot (left wins ties)
  float tv[16];
  int ti[16];
#pragma unroll
  for (int j = 0; j < 16; ++j) { tv[j] = __builtin_fabsf(dd[j]); ti[j] = 1 << j; }
#pragma unroll
  for (int w = 8; w >= 1; w >>= 1) {
#pragma unroll
    for (int j = 0; j < w; ++j) {
      bool L = tv[2 * j] >= tv[2 * j + 1];
      tv[j] = L ? tv[2 * j] : tv[2 * j + 1];
      ti[j] = L ? ti[2 * j] : ti[2 * j + 1];
    }
  }
  const int ohm = par ? ti[0] : 0;   // patch mask (0 when parity even)

  float sq[16];
#pragma unroll
  for (int j = 0; j < 16; ++j) {
    float X  = __builtin_fmaf(2.0f, f[j], cf[j]);      // exact int
    float s2 = __builtin_copysignf(2.0f, dd[j]);       // corr direction
    float bitf = (float)((ohm >> j) & 1);
    float Xp = __builtin_fmaf(bitf, s2, X);            // exact int
    float e  = __builtin_fmaf(-2.0f, xh[j], Xp);       // == fl(Xp - x)
    sq[j] = e * e;
    if (EMIT) y[j] = Xp * a;
  }
  float r0 = sq[0] + sq[8],  r1 = sq[1] + sq[9];
  float r2 = sq[2] + sq[10], r3 = sq[3] + sq[11];
  float r4 = sq[4] + sq[12], r5 = sq[5] + sq[13];
  float r6 = sq[6] + sq[14], r7 = sq[7] + sq[15];
  return ((r0 + r1) + (r2 + r3)) + ((r4 + r5) + (r6 + r7));
}

__global__ __launch_bounds__(256, 4) void bw_quant_kernel(
    const float* __restrict__ x_in,
    const float* __restrict__ C_rep,   // unused (constexpr codebook)
    const float* __restrict__ a_ptr,
    float* __restrict__ y_out,
    int n_rows)
{
#pragma clang fp contract(off)
  __shared__ alignas(16) float Cs[32][16];
  for (int i = threadIdx.x; i < 32 * 16; i += 256)
    Cs[i >> 4][i & 15] = (float)__builtin_popcount((i >> 4) & tb.m[i & 15]);
  __syncthreads();

  const int row = blockIdx.x * 256 + threadIdx.x;
  if (row >= n_rows) return;

  const float a = a_ptr[0];

  // -------- prologue: tables dd0/dd1, parity masks, sq0/delta -------------
  float dd0[16], dd1[16], g[16], sq0[16];
  int P0 = 0, P1 = 0;
  {
    const float4* xr4 = reinterpret_cast<const float4*>(x_in + (size_t)row * 16);
    float xv[16];
#pragma unroll
    for (int q = 0; q < 4; ++q) {
      float4 v = xr4[q];
      xv[q * 4 + 0] = v.x; xv[q * 4 + 1] = v.y;
      xv[q * 4 + 2] = v.z; xv[q * 4 + 3] = v.w;
    }
#pragma unroll
    for (int j = 0; j < 16; ++j) {
      float xj = xv[j] / a;
      float xh = xj * 0.5f;                 // exact
      float t0 = __builtin_rintf(xh);
      dd0[j] = xh - t0;
      float hm = xh - 0.5f;
      float t1 = __builtin_rintf(hm);
      dd1[j] = hm - t1;
      P0 |= ((int)t0 & 1) << j;
      P1 |= ((int)t1 & 1) << j;
      sq0[j] = dd0[j] * dd0[j];
      g[tb.pt[j]] = __builtin_fmaf(dd1[j], dd1[j], -sq0[j]);  // delta by point
    }
  }
  float S0 = (((sq0[0] + sq0[1]) + (sq0[2] + sq0[3])) + ((sq0[4] + sq0[5]) + (sq0[6] + sq0[7])))
           + (((sq0[8] + sq0[9]) + (sq0[10] + sq0[11])) + ((sq0[12] + sq0[13]) + (sq0[14] + sq0[15])));

  // fast WHT on g (4 stages, in place, all static indices)
#pragma unroll
  for (int s = 1; s < 16; s <<= 1) {
#pragma unroll
    for (int p = 0; p < 16; ++p) {
      if (!(p & s)) {
        float u = g[p], v = g[p | s];
        g[p] = u + v;
        g[p | s] = u - v;
      }
    }
  }
  float S1 = S0 + g[0];
  float h[16];
  h[0] = 0.0f;
#pragma unroll
  for (int t = 1; t < 16; ++t) h[t] = 0.5f * (g[0] - g[t]);

  // -------- pass 1: fully unrolled surrogate ranking, stable top-3 --------
  float b1 = __builtin_inff(), b2 = b1, b3 = b1;
  int k1 = 0, k2 = 0, k3 = 0;

#pragma unroll
  for (int k = 0; k < 32; ++k) {
    const unsigned w = tb.w[k];          // constant-folded (k is literal)
    const unsigned O = w & 0xFFFFu;
    const int p2 = (int)(w >> 16);
    const int kap = k >> 1;

    float s = (k & 1) ? (S1 - h[kap]) : (S0 + h[kap]);   // WHT ssum: 1 op

    float d[16];
#pragma unroll
    for (int j = 0; j < 16; ++j)
      d[j] = ((O >> j) & 1u) ? dd1[j] : dd0[j];          // literal-mask sel

    // mx = max |d| via v_max3 triples (abs folds as VOP3 src modifiers)
    float t0 = __builtin_fmaxf(__builtin_fmaxf(__builtin_fabsf(d[0]),  __builtin_fabsf(d[1])),  __builtin_fabsf(d[2]));
    float t1 = __builtin_fmaxf(__builtin_fmaxf(__builtin_fabsf(d[3]),  __builtin_fabsf(d[4])),  __builtin_fabsf(d[5]));
    float t2 = __builtin_fmaxf(__builtin_fmaxf(__builtin_fabsf(d[6]),  __builtin_fabsf(d[7])),  __builtin_fabsf(d[8]));
    float t3 = __builtin_fmaxf(__builtin_fmaxf(__builtin_fabsf(d[9]),  __builtin_fabsf(d[10])), __builtin_fabsf(d[11]));
    float t4 = __builtin_fmaxf(__builtin_fmaxf(__builtin_fabsf(d[12]), __builtin_fabsf(d[13])), __builtin_fabsf(d[14]));
    float mx = __builtin_fmaxf(__builtin_fmaxf(__builtin_fmaxf(t0, t1), t2),
                               __builtin_fmaxf(__builtin_fmaxf(t3, t4), __builtin_fabsf(d[15])));

    // mask parity (R5..R10-validated, surrogate only)
    unsigned sel = (O & (unsigned)P1) | (~O & (unsigned)P0);
    int cnt = __builtin_popcount(sel) + p2;
    float spen = s + __builtin_fmaf(-2.0f, mx, 1.0f);
    float dtil = (cnt & 1) ? spen : s;

    // stable top-3 insert (strict <: earlier k wins ties)
    bool lt1 = dtil < b1, lt2 = dtil < b2, lt3 = dtil < b3;
    float nb3 = lt3 ? (lt2 ? b2 : dtil) : b3;  int nk3 = lt3 ? (lt2 ? k2 : k) : k3;
    float nb2 = lt2 ? (lt1 ? b1 : dtil) : b2;  int nk2 = lt2 ? (lt1 ? k1 : k) : k2;
    b3 = nb3; k3 = nk3;
    b2 = nb2; k2 = nk2;
    b1 = lt1 ? dtil : b1;  k1 = lt1 ? k : k1;
  }

  // -------- pass 2: reload x (identical fl ops), exact evals --------------
  float xh[16];
  {
    const float4* xr4 = reinterpret_cast<const float4*>(x_in + (size_t)row * 16);
#pragma unroll
    for (int q = 0; q < 4; ++q) {
      float4 v = xr4[q];
      xh[q * 4 + 0] = (v.x / a) * 0.5f;
      xh[q * 4 + 1] = (v.y / a) * 0.5f;
      xh[q * 4 + 2] = (v.z / a) * 0.5f;
      xh[q * 4 + 3] = (v.w / a) * 0.5f;
    }
  }

  float ydummy[16];
  float D1 = eval_k<false>(k1, xh, a, ydummy, Cs);
  float D2 = eval_k<false>(k2, xh, a, ydummy, Cs);
  float D3 = eval_k<false>(k3, xh, a, ydummy, Cs);

  // lexicographic (D, k) == numpy first-min over the candidate set
  bool c2 = (D2 < D1) || (D2 == D1 && k2 < k1);
  float Db = c2 ? D2 : D1;
  int kb = c2 ? k2 : k1;
  bool c3 = (D3 < Db) || (D3 == Db && k3 < kb);
  kb = c3 ? k3 : kb;

  // -------- emit: exact re-eval of the winner -----------------------------
  float y[16];
  (void)eval_k<true>(kb, xh, a, y, Cs);

  float4* yr4 = reinterpret_cast<float4*>(y_out + (size_t)row * 16);
#pragma unroll
  for (int q = 0; q < 4; ++q) {
    float4 v;
    v.x = y[q * 4 + 0]; v.y = y[q * 4 + 1];
    v.z = y[q * 4 + 2]; v.w = y[q * 4 + 3];
    yr4[q] = v;
  }
}

extern "C" void kernel_launch(void* const* d_in, const int* in_sizes, int n_in,
                              void* d_out, int out_size, void* d_ws, size_t ws_size,
                              hipStream_t stream) {
  const float* x_in  = (const float*)d_in[0];
  const float* C_rep = (const float*)d_in[1];
  const float* a_ptr = (const float*)d_in[2];
  float* y_out = (float*)d_out;

  const int n_rows = in_sizes[0] / 16;
  const int block = 256;
  const int grid = (n_rows + block - 1) / block;
  bw_quant_kernel<<<grid, block, 0, stream>>>(x_in, C_rep, a_ptr, y_out, n_rows);
}